// Round 2
// baseline (2342.120 us; speedup 1.0000x reference)
//
#include <hip/hip_runtime.h>
#include <math.h>

#define NB 16
#define NC 64
#define HW 160
#define PLANE (HW * HW)              // 25600
#define SG 161                        // site grid (H+1)
#define NSITES (NB * SG * SG)         // 414736
#define NCONVBLK ((NSITES + 63) / 64) // 6481
#define OUT_LD_OFF (NB * NC * PLANE)  // 26214400 (logdet output offset)

// Map local submatrix index -> channel index for the INDS masks.
// n=64: identity. n=32: channels c%4 in {pa,pb}. n=16: c%4 == pa.
__device__ inline int chmap(int i, int n, int pa, int pb) {
    if (n == 64) return i;
    if (n == 32) return ((i >> 1) << 2) | ((i & 1) ? pb : pa);
    return (i << 2) | pa;
}

// One wave factorizes an n x n submatrix of W (LU, partial pivoting) in its
// private LDS region A (n*n floats) and returns log|det|. Wave-lockstep; the
// explicit s_waitcnt drains cross-lane LDS dependencies the compiler can't see.
__device__ float wave_lu_logabsdet(const float* __restrict__ W, float* A,
                                   int n, int sh, int pa, int pb, int lane) {
    for (int e = lane; e < n * n; e += 64) {
        int i = e >> sh, j = e & (n - 1);
        A[e] = W[chmap(i, n, pa, pb) * 64 + chmap(j, n, pa, pb)];
    }
    asm volatile("s_waitcnt lgkmcnt(0) vmcnt(0)" ::: "memory");
    float logdet = 0.f;
    for (int k = 0; k < n; ++k) {
        // --- pivot search over column k (rows >= k), 64-lane max+argmax ---
        float cand = -1.f;
        int idx = k;
        if (lane >= k && lane < n) {
            cand = fabsf(A[(lane << sh) + k]);
            idx = lane;
        }
        for (int off = 32; off; off >>= 1) {
            float oc = __shfl_down(cand, off, 64);
            int oi = __shfl_down(idx, off, 64);
            if (oc > cand) { cand = oc; idx = oi; }
        }
        int p = __shfl(idx, 0, 64);
        // --- swap rows k,p (lane = column) ---
        if (p != k && lane < n) {
            float tk = A[(k << sh) + lane];
            float tp = A[(p << sh) + lane];
            A[(k << sh) + lane] = tp;
            A[(p << sh) + lane] = tk;
        }
        asm volatile("s_waitcnt lgkmcnt(0)" ::: "memory");
        float piv = A[(k << sh) + k];  // broadcast read
        logdet += logf(fabsf(piv));
        float rpiv = 1.f / piv;
        float ckj = (lane < n) ? A[(k << sh) + lane] : 0.f;
        bool act = (lane > k) && (lane < n);
        for (int i2 = k + 1; i2 < n; ++i2) {
            float aik = A[(i2 << sh) + k];  // broadcast read (col k not updated here)
            float mult = aik * rpiv;
            if (act) A[(i2 << sh) + lane] = fmaf(-mult, ckj, A[(i2 << sh) + lane]);
        }
        asm volatile("s_waitcnt lgkmcnt(0)" ::: "memory");
    }
    return logdet;
}

__global__ __launch_bounds__(256) void InvConv1x1GridAlign_kernel(
    const float* __restrict__ x, const float* __restrict__ ld_in,
    const float* __restrict__ W, float* __restrict__ out) {
    // A64 doubles as the conv v-tile (64 channels x 64 sites)
    __shared__ float A64[64 * 64];
    __shared__ float A32a[32 * 32];
    __shared__ float A32b[32 * 32];
    __shared__ float A16[16 * 16];
    __shared__ float partial[4];

    if (blockIdx.x == 0) {
        // ---- determinant block: 9 slogdets, one wave per matrix group ----
        int wid = threadIdx.x >> 6;
        int lane = threadIdx.x & 63;
        float part = 0.f;
        if (wid == 0) {
            part = 25281.f * wave_lu_logabsdet(W, A64, 64, 6, 0, 0, lane);  // middle: 159*159 px
        } else if (wid == 1) {
            part  = wave_lu_logabsdet(W, A32a, 32, 5, 2, 3, lane);  // t: c%4 in {2,3}
            part += wave_lu_logabsdet(W, A32a, 32, 5, 0, 1, lane);  // b: {0,1}
            part *= 159.f;
        } else if (wid == 2) {
            part  = wave_lu_logabsdet(W, A32b, 32, 5, 1, 3, lane);  // l: {1,3}
            part += wave_lu_logabsdet(W, A32b, 32, 5, 0, 2, lane);  // r: {0,2}
            part *= 159.f;
        } else {
            part  = wave_lu_logabsdet(W, A16, 16, 4, 3, 0, lane);  // tl
            part += wave_lu_logabsdet(W, A16, 16, 4, 2, 0, lane);  // tr
            part += wave_lu_logabsdet(W, A16, 16, 4, 1, 0, lane);  // bl
            part += wave_lu_logabsdet(W, A16, 16, 4, 0, 0, lane);  // br
        }
        if (lane == 0) partial[wid] = part;
        __syncthreads();
        if (threadIdx.x < NB) {
            float dl = partial[0] + partial[1] + partial[2] + partial[3];
            out[OUT_LD_OFF + threadIdx.x] = ld_in[threadIdx.x] + dl;
        }
        return;
    }

    // ---- conv blocks: 64 sites/block; wave w handles outputs [16w,16w+16) ----
    int w = threadIdx.x >> 6;
    int l = threadIdx.x & 63;
    int s = (blockIdx.x - 1) * 64 + l;  // this lane's site, both phases
    bool live = s < NSITES;
    int sc = live ? s : 0;
    unsigned us = (unsigned)sc;
    unsigned b = us / (SG * SG);
    unsigned rr = us - b * (SG * SG);
    unsigned uy = rr / SG;
    int Y = (int)uy;
    int X = (int)(rr - uy * SG);

    const float* xb = x + (size_t)b * NC * PLANE;
    float* ob = out + (size_t)b * NC * PLANE;

    // quadrant validity + in-plane pixel offsets, quadrant m = 2*ic + jc
    bool okT = (Y >= 1), okB = (Y <= HW - 1), okL = (X >= 1), okR = (X <= HW - 1);
    bool vq[4] = {live && okT && okL, live && okT && okR,
                  live && okB && okL, live && okB && okR};
    int offq[4] = {(Y - 1) * HW + (X - 1), (Y - 1) * HW + X,
                   Y * HW + (X - 1), Y * HW + X};

    // Phase 1: gather channels c = 16w..16w+15 for site l into LDS v[c][site].
    // Lane = site -> coalesced global loads, 2-way LDS bank alias (free).
#pragma unroll
    for (int i = 0; i < 16; ++i) {
        int c = w * 16 + i;
        int m = c & 3;                         // quadrant
        float val = vq[m] ? xb[(size_t)(c ^ 3) * PLANE + offq[m]] : 0.f;
        A64[c * 64 + l] = val;
    }
    __syncthreads();

    // Phase 2: u[o] = sum_c W[o][c] * v[c] for this wave's 16 outputs.
    // W rows are wave-uniform -> scalar loads; v reads conflict-free.
    float u[16];
#pragma unroll
    for (int j = 0; j < 16; ++j) u[j] = 0.f;

#pragma unroll
    for (int cb = 0; cb < 4; ++cb) {
        float v[16];
#pragma unroll
        for (int i = 0; i < 16; ++i) v[i] = A64[(cb * 16 + i) * 64 + l];
#pragma unroll
        for (int j = 0; j < 16; ++j) {
            const float* wr = W + (size_t)(w * 16 + j) * 64 + cb * 16;
            float a = u[j];
#pragma unroll
            for (int k = 0; k < 16; ++k) a = fmaf(wr[k], v[k], a);
            u[j] = a;
        }
    }

    // Phase 3: scatter u[o] -> plane o^3, quadrant o&3. Coalesced along lanes.
#pragma unroll
    for (int j = 0; j < 16; ++j) {
        int o = w * 16 + j;
        int m = o & 3;
        if (vq[m]) ob[(size_t)(o ^ 3) * PLANE + offq[m]] = u[j];
    }
}

extern "C" void kernel_launch(void* const* d_in, const int* in_sizes, int n_in,
                              void* d_out, int out_size, void* d_ws, size_t ws_size,
                              hipStream_t stream) {
    const float* x = (const float*)d_in[0];
    const float* ld = (const float*)d_in[1];
    const float* W = (const float*)d_in[2];
    float* out = (float*)d_out;
    hipLaunchKernelGGL(InvConv1x1GridAlign_kernel, dim3(NCONVBLK + 1), dim3(256), 0,
                       stream, x, ld, W, out);
}

// Round 3
// 294.315 us; speedup vs baseline: 7.9579x; 7.9579x over previous
//
#include <hip/hip_runtime.h>
#include <math.h>

#define NB 16
#define NC 64
#define HW 160
#define PLANE (HW * HW)              // 25600
#define SG 161                        // site grid (H+1)
#define NSITES (NB * SG * SG)         // 414736
#define NCONVBLK ((NSITES + 63) / 64) // 6481
#define OUT_LD_OFF (NB * NC * PLANE)  // 26214400 (logdet output offset)

// Map local submatrix index -> channel index for the INDS masks.
// n=64: identity. n=32: channels c%4 in {pa,pb}. n=16: c%4 == pa.
__device__ inline int chmap(int i, int n, int pa, int pb) {
    if (n == 64) return i;
    if (n == 32) return ((i >> 1) << 2) | ((i & 1) ? pb : pa);
    return (i << 2) | pa;
}

// One wave factorizes an n x n submatrix of W (LU, partial pivoting) in its
// private LDS region A (n*n floats) and returns log|det|. Wave-lockstep; the
// explicit s_waitcnt drains cross-lane LDS dependencies the compiler can't see.
__device__ float wave_lu_logabsdet(const float* __restrict__ W, float* A,
                                   int n, int sh, int pa, int pb, int lane) {
    for (int e = lane; e < n * n; e += 64) {
        int i = e >> sh, j = e & (n - 1);
        A[e] = W[chmap(i, n, pa, pb) * 64 + chmap(j, n, pa, pb)];
    }
    asm volatile("s_waitcnt lgkmcnt(0) vmcnt(0)" ::: "memory");
    float logdet = 0.f;
    for (int k = 0; k < n; ++k) {
        // --- pivot search over column k (rows >= k), 64-lane max+argmax ---
        float cand = -1.f;
        int idx = k;
        if (lane >= k && lane < n) {
            cand = fabsf(A[(lane << sh) + k]);
            idx = lane;
        }
        for (int off = 32; off; off >>= 1) {
            float oc = __shfl_down(cand, off, 64);
            int oi = __shfl_down(idx, off, 64);
            if (oc > cand) { cand = oc; idx = oi; }
        }
        int p = __shfl(idx, 0, 64);
        // --- swap rows k,p (lane = column) ---
        if (p != k && lane < n) {
            float tk = A[(k << sh) + lane];
            float tp = A[(p << sh) + lane];
            A[(k << sh) + lane] = tp;
            A[(p << sh) + lane] = tk;
        }
        asm volatile("s_waitcnt lgkmcnt(0)" ::: "memory");
        float piv = A[(k << sh) + k];  // broadcast read
        logdet += logf(fabsf(piv));
        float rpiv = 1.f / piv;
        float ckj = (lane < n) ? A[(k << sh) + lane] : 0.f;
        bool act = (lane > k) && (lane < n);
        for (int i2 = k + 1; i2 < n; ++i2) {
            float aik = A[(i2 << sh) + k];  // broadcast read (col k not updated here)
            float mult = aik * rpiv;
            if (act) A[(i2 << sh) + lane] = fmaf(-mult, ckj, A[(i2 << sh) + lane]);
        }
        asm volatile("s_waitcnt lgkmcnt(0)" ::: "memory");
    }
    return logdet;
}

__global__ __launch_bounds__(256, 6) void InvConv1x1GridAlign_kernel(
    const float* __restrict__ x, const float* __restrict__ ld_in,
    const float* __restrict__ W, float* __restrict__ out) {
    // A64 doubles as the conv v-tile (64 channels x 64 sites)
    __shared__ float A64[64 * 64];
    __shared__ float A32a[32 * 32];
    __shared__ float A32b[32 * 32];
    __shared__ float A16[16 * 16];
    __shared__ float partial[4];

    if (blockIdx.x == 0) {
        // ---- determinant block: 9 slogdets, one wave per matrix group ----
        int wid = threadIdx.x >> 6;
        int lane = threadIdx.x & 63;
        float part = 0.f;
        if (wid == 0) {
            part = 25281.f * wave_lu_logabsdet(W, A64, 64, 6, 0, 0, lane);  // middle: 159*159 px
        } else if (wid == 1) {
            part  = wave_lu_logabsdet(W, A32a, 32, 5, 2, 3, lane);  // t: c%4 in {2,3}
            part += wave_lu_logabsdet(W, A32a, 32, 5, 0, 1, lane);  // b: {0,1}
            part *= 159.f;
        } else if (wid == 2) {
            part  = wave_lu_logabsdet(W, A32b, 32, 5, 1, 3, lane);  // l: {1,3}
            part += wave_lu_logabsdet(W, A32b, 32, 5, 0, 2, lane);  // r: {0,2}
            part *= 159.f;
        } else {
            part  = wave_lu_logabsdet(W, A16, 16, 4, 3, 0, lane);  // tl
            part += wave_lu_logabsdet(W, A16, 16, 4, 2, 0, lane);  // tr
            part += wave_lu_logabsdet(W, A16, 16, 4, 1, 0, lane);  // bl
            part += wave_lu_logabsdet(W, A16, 16, 4, 0, 0, lane);  // br
        }
        if (lane == 0) partial[wid] = part;
        __syncthreads();
        if (threadIdx.x < NB) {
            float dl = partial[0] + partial[1] + partial[2] + partial[3];
            out[OUT_LD_OFF + threadIdx.x] = ld_in[threadIdx.x] + dl;
        }
        return;
    }

    // ---- conv blocks: 64 sites/block; wave w handles channels/outputs
    //      [16w, 16w+16). All quadrant selection via compile-time literals. ----
    int w = threadIdx.x >> 6;
    int l = threadIdx.x & 63;
    int s = (blockIdx.x - 1) * 64 + l;  // this lane's site, all phases
    bool live = s < NSITES;
    int sc = live ? s : 0;
    unsigned us = (unsigned)sc;
    unsigned b = us / (SG * SG);
    unsigned rr = us - b * (SG * SG);
    unsigned uy = rr / SG;
    int Y = (int)uy;
    int X = (int)(rr - uy * SG);

    const float* xb = x + (size_t)b * NC * PLANE;
    float* ob = out + (size_t)b * NC * PLANE;

    // quadrant validity + in-plane pixel offsets, quadrant m = 2*ic + jc
    bool okT = (Y >= 1), okB = (Y <= HW - 1), okL = (X >= 1), okR = (X <= HW - 1);
    bool v00 = live && okT && okL, v01 = live && okT && okR;
    bool v10 = live && okB && okL, v11 = live && okB && okR;
    int off00 = (Y - 1) * HW + (X - 1);
    int off01 = (Y - 1) * HW + X;
    int off10 = Y * HW + (X - 1);
    int off11 = Y * HW + X;

    // Phase 1: gather channels c = 16w+4g+m (m literal) into LDS v[c][site].
    // Z-channel c reads input plane c^3 at quadrant m=c&3. Lane = site ->
    // coalesced global loads; LDS 2-way bank alias (free).
    {
        const float* xw = xb + (size_t)w * 16 * PLANE;
        float* Arow = A64 + w * 16 * 64 + l;
#pragma unroll
        for (int g = 0; g < 4; ++g) {
            const float* pg = xw + (size_t)g * 4 * PLANE;
            Arow[(g * 4 + 0) * 64] = v00 ? pg[3 * PLANE + off00] : 0.f;
            Arow[(g * 4 + 1) * 64] = v01 ? pg[2 * PLANE + off01] : 0.f;
            Arow[(g * 4 + 2) * 64] = v10 ? pg[1 * PLANE + off10] : 0.f;
            Arow[(g * 4 + 3) * 64] = v11 ? pg[0 * PLANE + off11] : 0.f;
        }
    }
    __syncthreads();

    // Phase 2: u[j] = sum_c W[16w+j][c] * v[c]. Row base made explicitly
    // wave-uniform via readfirstlane so W loads compile to s_load (SGPR
    // operands in the FMAs, no per-lane VMEM).
    int wu = __builtin_amdgcn_readfirstlane(w);
    const float* Wbase = W + (size_t)wu * 16 * 64;
    float u[16];
#pragma unroll
    for (int j = 0; j < 16; ++j) u[j] = 0.f;

#pragma unroll
    for (int cb = 0; cb < 4; ++cb) {
        float v[16];
#pragma unroll
        for (int i = 0; i < 16; ++i) v[i] = A64[(cb * 16 + i) * 64 + l];
#pragma unroll
        for (int j = 0; j < 16; ++j) {
            const float* wr = Wbase + j * 64 + cb * 16;
            float a = u[j];
#pragma unroll
            for (int k = 0; k < 16; ++k) a = fmaf(wr[k], v[k], a);
            u[j] = a;
        }
    }

    // Phase 3: scatter u[j] (o = 16w+4g+m) -> plane o^3, quadrant m literal.
    {
        float* ow = ob + (size_t)w * 16 * PLANE;
#pragma unroll
        for (int g = 0; g < 4; ++g) {
            float* pg = ow + (size_t)g * 4 * PLANE;
            if (v00) pg[3 * PLANE + off00] = u[g * 4 + 0];
            if (v01) pg[2 * PLANE + off01] = u[g * 4 + 1];
            if (v10) pg[1 * PLANE + off10] = u[g * 4 + 2];
            if (v11) pg[0 * PLANE + off11] = u[g * 4 + 3];
        }
    }
}

extern "C" void kernel_launch(void* const* d_in, const int* in_sizes, int n_in,
                              void* d_out, int out_size, void* d_ws, size_t ws_size,
                              hipStream_t stream) {
    const float* x = (const float*)d_in[0];
    const float* ld = (const float*)d_in[1];
    const float* W = (const float*)d_in[2];
    float* out = (float*)d_out;
    hipLaunchKernelGGL(InvConv1x1GridAlign_kernel, dim3(NCONVBLK + 1), dim3(256), 0,
                       stream, x, ld, W, out);
}